// Round 9
// baseline (154.906 us; speedup 1.0000x reference)
//
#include <hip/hip_runtime.h>
#include <stdint.h>
#include <math.h>

// SFIS: F=16, D=64, N=100000, B=2048, ORDER=3, BETA=1e-4, H=64
#define NB    2048
#define NE    680     // 120 pairs + 560 triples
#define L1N   120
#define KEEP2 455     // triples with A<=12 feed the regularizer
#define PVS   68      // table row stride in floats (16B-aligned, bank-spread)
#define NT    43      // 16-row MFMA tiles covering 688 >= 680 rows
#define NSL   688     // NT*16

#define THREEFRY_PARTITIONABLE 1

typedef __attribute__((ext_vector_type(8))) short bf16x8;
typedef __attribute__((ext_vector_type(4))) float f32x4;

union ABfrag { bf16x8 v; uint32_t u[4]; };

__device__ __forceinline__ uint32_t rotl32(uint32_t v, uint32_t d) {
  return (v << d) | (v >> (32u - d));
}

// f32 -> bf16 bits, round-nearest-even (finite inputs only)
__device__ __forceinline__ uint32_t bf_rne(float f) {
  uint32_t u = __float_as_uint(f);
  return (u + 0x7fffu + ((u >> 16) & 1u)) >> 16;
}

// JAX threefry2x32 (jax/_src/prng.py), 20 rounds.
__device__ __forceinline__ void tf2x32(uint32_t k0, uint32_t k1,
                                       uint32_t c0, uint32_t c1,
                                       uint32_t &o0, uint32_t &o1) {
  uint32_t ks2 = k0 ^ k1 ^ 0x1BD11BDAu;
  uint32_t x0 = c0 + k0;
  uint32_t x1 = c1 + k1;
#define TF_R(r) { x0 += x1; x1 = rotl32(x1, r); x1 ^= x0; }
  TF_R(13) TF_R(15) TF_R(26) TF_R(6)
  x0 += k1;  x1 += ks2 + 1u;
  TF_R(17) TF_R(29) TF_R(16) TF_R(24)
  x0 += ks2; x1 += k0 + 2u;
  TF_R(13) TF_R(15) TF_R(26) TF_R(6)
  x0 += k0;  x1 += k1 + 3u;
  TF_R(17) TF_R(29) TF_R(16) TF_R(24)
  x0 += k1;  x1 += ks2 + 4u;
  TF_R(13) TF_R(15) TF_R(26) TF_R(6)
  x0 += ks2; x1 += k0 + 5u;
#undef TF_R
  o0 = x0; o1 = x1;
}

// 512 threads. 2nd arg = 2: VGPR cap >=128 under either toolchain
// interpretation (R8's (512,4) forced 64 regs -> 260 MB/dispatch spill).
// LDS 74 KB admits 2 blocks/CU; VGPR <=128 keeps both resident.
__global__ __launch_bounds__(512, 2) void sfis_main(
    const int*   __restrict__ x,
    const float* __restrict__ M,
    const float* __restrict__ w0,
    const float* __restrict__ w_table,
    const float* __restrict__ V_table,
    const float* __restrict__ Z_table,
    const float* __restrict__ W1,
    const float* __restrict__ b1,
    const float* __restrict__ W2,
    const float* __restrict__ b2,
    float* __restrict__ out,
    float* __restrict__ reg_partial) {
  // Product tables: rows 0-15 = V0f/Z0f fields, 16 = ones,
  // 17+m (m = a1*(a1+1)/2 + k1, a1<=13) = row(a1+1) * row(k1)  [level-1 kept pairs]
  __shared__ __align__(16) float PV[123 * PVS];
  __shared__ __align__(16) float PZ[123 * PVS];
  __shared__ unsigned short descs16[NSL];
  __shared__ float wts[NSL];
  __shared__ float t2s[NSL];
  __shared__ float W2s[64];
  __shared__ int xs[16];
  __shared__ float redY[8], redV[8];
  __shared__ float wsum_s, w2sum_s;

  const int b   = blockIdx.x;
  const int tid = threadIdx.x;

  // ---- phase A: indices, ones rows, descriptors ----
  if (tid < 16) xs[tid] = x[b * 16 + tid];
  if (tid < 64) {
    W2s[tid] = W2[tid];
    PV[16 * PVS + tid] = 1.f;
    PZ[16 * PVS + tid] = 1.f;
  }
  for (int e = tid; e < NSL; e += 512) {
    int fi, prow, lvl;
    if (e < L1N) {                      // pair: row(a+1) * row(k)
      int a = 0;
      while ((a + 1) * (a + 2) / 2 <= e) ++a;
      int k = e - a * (a + 1) / 2;
      fi = a + 1; prow = k; lvl = 0;
    } else if (e < NE) {                // triple: row(A+2) * pairproduct(k)
      int e2 = e - L1N;
      int A = 0;
      while ((A + 1) * (A + 2) * (A + 3) / 6 <= e2) ++A;
      int k = e2 - A * (A + 1) * (A + 2) / 6;   // kept-pair index 0..104
      fi = A + 2; prow = 17 + k; lvl = 1;
    } else {                            // dummy rows 680..687 -> ones*ones
      fi = 16; prow = 16; lvl = 0;
    }
    descs16[e] = (unsigned short)((uint32_t)fi | ((uint32_t)prow << 5) |
                                  ((uint32_t)lvl << 12));
  }
  __syncthreads();

  // ---- phase C: V0f = M @ V, Z0f = M @ Z into table rows 0..15 ----
  if (tid == 0) {
    float s = 0.f, s2 = 0.f;
    for (int f = 0; f < 16; ++f) {
      float wv = w_table[xs[f]];
      s += wv; s2 += wv * wv;
    }
    wsum_s = s; w2sum_s = s2;
  }
  for (int idx = tid; idx < 1024; idx += 512) {
    int f = idx >> 6, d = idx & 63;
    float av = 0.f, az = 0.f;
    for (int g = 0; g < 16; ++g) {
      float m = M[f * 16 + g];          // wave-uniform -> s_load
      long off = (long)xs[g] * 64 + d;  // coalesced over d
      av = fmaf(m, V_table[off], av);
      az = fmaf(m, Z_table[off], az);
    }
    PV[f * PVS + d] = av;
    PZ[f * PVS + d] = az;
  }
  __syncthreads();

  // ---- phase P: 105 level-1 pair-product rows (exactly reference's *_cur) ----
  for (int idx = tid; idx < 105 * 64; idx += 512) {
    int m = idx >> 6, d = idx & 63;
    int a1 = 0;
    while ((a1 + 1) * (a1 + 2) / 2 <= m) ++a1;
    int k1 = m - a1 * (a1 + 1) / 2;
    PV[(17 + m) * PVS + d] = PV[(a1 + 1) * PVS + d] * PV[k1 * PVS + d];
    PZ[(17 + m) * PVS + d] = PZ[(a1 + 1) * PVS + d] * PZ[k1 * PVS + d];
  }
  __syncthreads();

  // ---- phase D1: Wt / vsq on VALU (2 rows, 1 mul per element) ----
  float v2acc = 0.f;
  for (int e0 = 0; e0 < 1024; e0 += 512) {
    const int e = e0 + tid;
    if (e < NE) {
      uint32_t dsc = descs16[e];
      const int oI = (int)(dsc & 31) * PVS;
      const int oP = (int)((dsc >> 5) & 127) * PVS;
      const int lvl = (dsc >> 12) & 1;

      float wt = 0.f, vsq = 0.f;
      for (int dq = 0; dq < 16; ++dq) {
        float4 pv = *(const float4*)&PV[oP + (dq << 2)];
        float4 vi = *(const float4*)&PV[oI + (dq << 2)];
        float p0 = vi.x * pv.x;
        float p1 = vi.y * pv.y;
        float p2 = vi.z * pv.z;
        float p3 = vi.w * pv.w;
        wt  += p0 + p1 + p2 + p3;
        vsq += p0 * p0 + p1 * p1 + p2 * p2 + p3 * p3;
      }
      wts[e] = wt;
      if (lvl && (uint32_t)(e - L1N) < (uint32_t)KEEP2) v2acc += vsq;
    }
  }

  // ---- phase D2: MLP hidden layer, bf16x3 MFMA GEMM (h = Z_sel@W1 + b1) ----
  // acc += Ah*Bh + Al*Bh + Ah*Bl (same order/values as R5-R7: z = zi*(zj*zl)
  // with inner product from PZ). Bh+Bl both in registers (64 VGPR).
  {
    const int lane = tid & 63;
    const int wave = tid >> 6;
    const int col  = lane & 15;   // A-row / D-col / B-col within 16-tile
    const int kg   = lane >> 4;   // k-group: this lane's 8 contiguous k

    bf16x8 Bh[2][4], Bl[2][4];
#pragma unroll
    for (int ks = 0; ks < 2; ++ks)
#pragma unroll
      for (int c = 0; c < 4; ++c) {
        const float* wp = &W1[(ks * 32 + kg * 8) * 64 + c * 16 + col];
#pragma unroll
        for (int j = 0; j < 8; ++j) {
          float w = wp[j * 64];
          uint32_t hb = bf_rne(w);
          Bh[ks][c][j] = (short)hb;
          float hf = __uint_as_float(hb << 16);
          Bl[ks][c][j] = (short)bf_rne(w - hf);
        }
      }
    float bv0 = b1[col], bv1 = b1[16 + col], bv2 = b1[32 + col], bv3 = b1[48 + col];

    for (int t = wave; t < NT; t += 8) {
      const int er = 16 * t + col;
      const uint32_t dsc = (uint32_t)descs16[er];
      const int oI = (int)(dsc & 31) * PVS;
      const int oP = (int)((dsc >> 5) & 127) * PVS;

      f32x4 acc[4];
      acc[0] = (f32x4){bv0, bv0, bv0, bv0};
      acc[1] = (f32x4){bv1, bv1, bv1, bv1};
      acc[2] = (f32x4){bv2, bv2, bv2, bv2};
      acc[3] = (f32x4){bv3, bv3, bv3, bv3};

#pragma unroll
      for (int ks = 0; ks < 2; ++ks) {
        const int kc = ks * 32 + kg * 8;
        float4 z0 = *(const float4*)&PZ[oI + kc];
        float4 z1 = *(const float4*)&PZ[oI + kc + 4];
        float4 q0 = *(const float4*)&PZ[oP + kc];
        float4 q1 = *(const float4*)&PZ[oP + kc + 4];
        float z[8];
        z[0] = z0.x * q0.x;  z[1] = z0.y * q0.y;
        z[2] = z0.z * q0.z;  z[3] = z0.w * q0.w;
        z[4] = z1.x * q1.x;  z[5] = z1.y * q1.y;
        z[6] = z1.z * q1.z;  z[7] = z1.w * q1.w;

        ABfrag Ah, Al;
#pragma unroll
        for (int p = 0; p < 4; ++p) {
          uint32_t uz0 = __float_as_uint(z[2 * p]);
          uint32_t uz1 = __float_as_uint(z[2 * p + 1]);
          Ah.u[p] = __builtin_amdgcn_perm(uz1, uz0, 0x07060302u);
          float hf0 = __uint_as_float(uz0 & 0xffff0000u);
          float hf1 = __uint_as_float(uz1 & 0xffff0000u);
          uint32_t d0 = __float_as_uint(z[2 * p]     - hf0);
          uint32_t d1 = __float_as_uint(z[2 * p + 1] - hf1);
          d0 = d0 + 0x7fffu + ((d0 >> 16) & 1u);   // rne to bf16 (in hi word)
          d1 = d1 + 0x7fffu + ((d1 >> 16) & 1u);
          Al.u[p] = __builtin_amdgcn_perm(d1, d0, 0x07060302u);
        }
#pragma unroll
        for (int c = 0; c < 4; ++c)
          acc[c] = __builtin_amdgcn_mfma_f32_16x16x32_bf16(Ah.v, Bh[ks][c], acc[c], 0, 0, 0);
#pragma unroll
        for (int c = 0; c < 4; ++c)
          acc[c] = __builtin_amdgcn_mfma_f32_16x16x32_bf16(Al.v, Bh[ks][c], acc[c], 0, 0, 0);
#pragma unroll
        for (int c = 0; c < 4; ++c)
          acc[c] = __builtin_amdgcn_mfma_f32_16x16x32_bf16(Ah.v, Bl[ks][c], acc[c], 0, 0, 0);
      }

      // second layer: t2 = relu(h) @ W2, reduced across the 16 cols
      float p0 = 0.f, p1 = 0.f, p2 = 0.f, p3 = 0.f;
#pragma unroll
      for (int c = 0; c < 4; ++c) {
        float w2v = W2s[c * 16 + col];
        p0 = fmaf(fmaxf(acc[c][0], 0.f), w2v, p0);
        p1 = fmaf(fmaxf(acc[c][1], 0.f), w2v, p1);
        p2 = fmaf(fmaxf(acc[c][2], 0.f), w2v, p2);
        p3 = fmaf(fmaxf(acc[c][3], 0.f), w2v, p3);
      }
#pragma unroll
      for (int m = 1; m < 16; m <<= 1) {
        p0 += __shfl_xor(p0, m, 16);
        p1 += __shfl_xor(p1, m, 16);
        p2 += __shfl_xor(p2, m, 16);
        p3 += __shfl_xor(p3, m, 16);
      }
      const int rb = 16 * t + kg * 4;   // D rows this lane-group owns
      if      (col == 0) t2s[rb + 0] = p0;
      else if (col == 1) t2s[rb + 1] = p1;
      else if (col == 2) t2s[rb + 2] = p2;
      else if (col == 3) t2s[rb + 3] = p3;
    }
  }
  __syncthreads();

  // ---- phase D3: eps (threefry), sigmoid (fast f32 + guarded f64), gate ----
  uint32_t fkA0, fkA1, fkB0, fkB1;   // fold_in(key(42), 0) and (.,1)
  tf2x32(0u, 42u, 0u, 0u, fkA0, fkA1);
  tf2x32(0u, 42u, 0u, 1u, fkB0, fkB1);
  const float b2v = b2[0];

  float yacc = 0.f;
  for (int e0 = 0; e0 < 1024; e0 += 512) {
    const int e = e0 + tid;
    if (e < NE) {
      uint32_t dsc = descs16[e];
      const int lvl = (dsc >> 12) & 1;
      float t2 = t2s[e] + b2v;

      uint32_t Lsz  = lvl ? 560u : 120u;
      uint32_t lidx = lvl ? (uint32_t)(e - L1N) : (uint32_t)e;
      uint32_t kk0  = lvl ? fkB0 : fkA0;
      uint32_t kk1  = lvl ? fkB1 : fkA1;
      uint32_t gi   = (uint32_t)b * Lsz + lidx;
      uint32_t o0, o1, bits;
#if THREEFRY_PARTITIONABLE
      tf2x32(kk0, kk1, 0u, gi, o0, o1);
      bits = o0 ^ o1;
#else
      {
        uint32_t half = Lsz * (NB / 2);
        if (gi < half) { tf2x32(kk0, kk1, gi, gi + half, o0, o1); bits = o0; }
        else           { tf2x32(kk0, kk1, gi - half, gi, o0, o1); bits = o1; }
      }
#endif
      float eps = __uint_as_float((bits >> 9) | 0x3f800000u) - 1.0f;

      // fast f32 sigmoid; exact f64 only in the ambiguity window. Decisions
      // identical to the pure-f64 path: |pf - pro_f64| < ~3e-6 << 1e-4.
      float pf = 1.0f / (1.0f + __expf(-t2));
      bool gate;
      if (fabsf(pf - eps) > 1e-4f) {
        gate = (pf >= eps);
      } else {
        double ex = exp(-(double)t2);
        float pro = (float)(1.0 / (1.0 + ex));
        gate = (pro >= eps);
      }
      if (gate) yacc += wts[e];
    }
  }

  // ---- phase E: wave-shuffle reduction, one barrier ----
  {
#pragma unroll
    for (int m = 32; m > 0; m >>= 1) {
      yacc  += __shfl_down(yacc, m, 64);
      v2acc += __shfl_down(v2acc, m, 64);
    }
    if ((tid & 63) == 0) {
      redY[tid >> 6] = yacc;
      redV[tid >> 6] = v2acc;
    }
    __syncthreads();
    if (tid == 0) {
      float ys = 0.f, vs = 0.f;
#pragma unroll
      for (int wv = 0; wv < 8; ++wv) { ys += redY[wv]; vs += redV[wv]; }
      out[b] = w0[0] + wsum_s + ys;
      reg_partial[b] = w2sum_s + vs;
    }
  }
}

__global__ __launch_bounds__(256) void sfis_reduce(
    const float* __restrict__ reg_partial, float* __restrict__ out) {
  __shared__ float red[256];
  int tid = threadIdx.x;
  float s = 0.f;
  for (int i = tid; i < NB; i += 256) s += reg_partial[i];
  red[tid] = s;
  __syncthreads();
  for (int st = 128; st > 0; st >>= 1) {
    if (tid < st) red[tid] += red[tid + st];
    __syncthreads();
  }
  if (tid == 0) out[NB] = 1.0e-4f * red[0];  // BETA
}

extern "C" void kernel_launch(void* const* d_in, const int* in_sizes, int n_in,
                              void* d_out, int out_size, void* d_ws, size_t ws_size,
                              hipStream_t stream) {
  (void)in_sizes; (void)n_in; (void)out_size; (void)ws_size;
  const int*   x       = (const int*)  d_in[0];
  const float* M       = (const float*)d_in[1];
  const float* w0      = (const float*)d_in[2];
  const float* w_table = (const float*)d_in[3];
  const float* V_table = (const float*)d_in[4];
  const float* Z_table = (const float*)d_in[5];
  const float* W1      = (const float*)d_in[6];
  const float* b1      = (const float*)d_in[7];
  const float* W2      = (const float*)d_in[8];
  const float* b2      = (const float*)d_in[9];
  float* out  = (float*)d_out;
  float* regp = (float*)d_ws;   // 2048 partials

  hipLaunchKernelGGL(sfis_main, dim3(NB), dim3(512), 0, stream,
                     x, M, w0, w_table, V_table, Z_table, W1, b1, W2, b2,
                     out, regp);
  hipLaunchKernelGGL(sfis_reduce, dim3(1), dim3(256), 0, stream, regp, out);
}

// Round 10
// 87.620 us; speedup vs baseline: 1.7679x; 1.7679x over previous
//
#include <hip/hip_runtime.h>
#include <stdint.h>
#include <math.h>

// SFIS: F=16, D=64, N=100000, B=2048, ORDER=3, BETA=1e-4, H=64
#define NB    2048
#define NE    680     // 120 pairs + 560 triples
#define L1N   120
#define L2N   560
#define KEEP2 455     // triples with A<=12 feed the regularizer
#define ROWP  68      // padded LDS row stride (floats) for V0s/Z0s
#define NT    43      // 16-row MFMA tiles covering 688 >= 680 rows
#define WLOS  72      // W1loT row stride in ushorts (pad: bank-balanced b128)

#define THREEFRY_PARTITIONABLE 1

typedef __attribute__((ext_vector_type(8))) short bf16x8;
typedef __attribute__((ext_vector_type(4))) float f32x4;

union ABfrag { bf16x8 v; uint32_t u[4]; };

__device__ __forceinline__ uint32_t rotl32(uint32_t v, uint32_t d) {
  return (v << d) | (v >> (32u - d));
}

// f32 -> bf16 bits, round-nearest-even (finite inputs only)
__device__ __forceinline__ uint32_t bf_rne(float f) {
  uint32_t u = __float_as_uint(f);
  return (u + 0x7fffu + ((u >> 16) & 1u)) >> 16;
}

// JAX threefry2x32 (jax/_src/prng.py), 20 rounds.
__device__ __forceinline__ void tf2x32(uint32_t k0, uint32_t k1,
                                       uint32_t c0, uint32_t c1,
                                       uint32_t &o0, uint32_t &o1) {
  uint32_t ks2 = k0 ^ k1 ^ 0x1BD11BDAu;
  uint32_t x0 = c0 + k0;
  uint32_t x1 = c1 + k1;
#define TF_R(r) { x0 += x1; x1 = rotl32(x1, r); x1 ^= x0; }
  TF_R(13) TF_R(15) TF_R(26) TF_R(6)
  x0 += k1;  x1 += ks2 + 1u;
  TF_R(17) TF_R(29) TF_R(16) TF_R(24)
  x0 += ks2; x1 += k0 + 2u;
  TF_R(13) TF_R(15) TF_R(26) TF_R(6)
  x0 += k0;  x1 += k1 + 3u;
  TF_R(17) TF_R(29) TF_R(16) TF_R(24)
  x0 += k1;  x1 += ks2 + 4u;
  TF_R(13) TF_R(15) TF_R(26) TF_R(6)
  x0 += ks2; x1 += k0 + 5u;
#undef TF_R
  o0 = x0; o1 = x1;
}

// R7 champion shape: 256 threads, 25.5 KB LDS (6 blocks/CU), Bh in regs,
// Bl streamed from LDS. VGPR ~80. Do NOT grow LDS or merge phases (R6/R8/R9).
__global__ __launch_bounds__(256, 8) void sfis_main(
    const int*   __restrict__ x,
    const float* __restrict__ M,
    const float* __restrict__ w0,
    const float* __restrict__ w_table,
    const float* __restrict__ V_table,
    const float* __restrict__ Z_table,
    const float* __restrict__ W1,
    const float* __restrict__ b1,
    const float* __restrict__ W2,
    const float* __restrict__ b2,
    float* __restrict__ out,
    float* __restrict__ reg_partial) {
  __shared__ __align__(16) float V0s[17 * ROWP];  // row 16 = ones
  __shared__ __align__(16) float Z0s[17 * ROWP];
  __shared__ __align__(16) unsigned short W1loT[64 * WLOS]; // lo-split of W1, transposed [n][k]
  __shared__ unsigned short descs16[NT * 16];
  __shared__ float wts[NT * 16];
  __shared__ float t2s[NT * 16];
  __shared__ float W2s[64];
  __shared__ int xs[16];
  __shared__ float red8[8];
  __shared__ float wsum_s, w2sum_s;

  const int b   = blockIdx.x;
  const int tid = threadIdx.x;

  // ---- phase A: indices, ones rows, descriptors, W1 lo-split table ----
  if (tid < 16) xs[tid] = x[b * 16 + tid];
  if (tid < 64) {
    W2s[tid] = W2[tid];
    V0s[16 * ROWP + tid] = 1.f;
    Z0s[16 * ROWP + tid] = 1.f;
  }
  for (int e = tid; e < NT * 16; e += 256) {
    int fi, fj, fl, lvl;
    if (e < L1N) {                      // pair: V0f[a+1] * V0f[k]
      int a = 0;
      while ((a + 1) * (a + 2) / 2 <= e) ++a;
      int k = e - a * (a + 1) / 2;
      fi = a + 1; fj = k; fl = 16; lvl = 0;   // fl=16 -> ones row
    } else if (e < NE) {                // triple: V0f[A+2] * (V0f[a1+1]*V0f[k1])
      int e2 = e - L1N;
      int A = 0;
      while ((A + 1) * (A + 2) * (A + 3) / 6 <= e2) ++A;
      int k = e2 - A * (A + 1) * (A + 2) / 6;
      int a1 = 0;
      while ((a1 + 1) * (a1 + 2) / 2 <= k) ++a1;
      int k1 = k - a1 * (a1 + 1) / 2;
      fi = A + 2; fj = a1 + 1; fl = k1; lvl = 1;
    } else {                            // dummy rows 680..687 -> ones product
      fi = 16; fj = 16; fl = 16; lvl = 0;
    }
    descs16[e] = (unsigned short)((uint32_t)fi | ((uint32_t)fj << 5) |
                                  ((uint32_t)fl << 10) | ((uint32_t)lvl << 15));
  }
  // W1loT[n*WLOS + k] = bf16_rne(W1[k][n] - bf16_hi(W1[k][n]))
  for (int i = tid; i < 4096; i += 256) {
    int n = i & 63, k = i >> 6;
    float w = W1[i];
    uint32_t hb = bf_rne(w);
    float hf = __uint_as_float(hb << 16);
    W1loT[n * WLOS + k] = (unsigned short)bf_rne(w - hf);
  }
  __syncthreads();

  // ---- phase C: V0f = M @ V, Z0f = M @ Z (from global; rows are L1-hot) ----
  if (tid == 0) {
    float s = 0.f, s2 = 0.f;
    for (int f = 0; f < 16; ++f) {
      float wv = w_table[xs[f]];
      s += wv; s2 += wv * wv;
    }
    wsum_s = s; w2sum_s = s2;
  }
  for (int idx = tid; idx < 1024; idx += 256) {
    int f = idx >> 6, d = idx & 63;
    float av = 0.f, az = 0.f;
    for (int g = 0; g < 16; ++g) {
      float m = M[f * 16 + g];          // wave-uniform -> s_load
      long off = (long)xs[g] * 64 + d;  // coalesced over d
      av = fmaf(m, V_table[off], av);
      az = fmaf(m, Z_table[off], az);
    }
    V0s[f * ROWP + d] = av;
    Z0s[f * ROWP + d] = az;
  }
  __syncthreads();

  // ---- phase D1: Wt / vsq on VALU; Wt -> LDS ----
  float v2acc = 0.f;
  for (int e0 = 0; e0 < 768; e0 += 256) {
    const int e = e0 + tid;
    const bool valid = (e < NE);
    uint32_t dsc = valid ? (uint32_t)descs16[e] : 0x4210u;
    const int oI = (int)(dsc & 31) * ROWP;
    const int oJ = (int)((dsc >> 5) & 31) * ROWP;
    const int oL = (int)((dsc >> 10) & 31) * ROWP;
    const int lvl = (dsc >> 15) & 1;

    float wt = 0.f, vsq = 0.f;
    for (int dq = 0; dq < 16; ++dq) {
      float4 a = *(const float4*)&V0s[oJ + (dq << 2)];
      float4 c = *(const float4*)&V0s[oL + (dq << 2)];
      float4 v = *(const float4*)&V0s[oI + (dq << 2)];
      float p0 = v.x * (a.x * c.x);
      float p1 = v.y * (a.y * c.y);
      float p2 = v.z * (a.z * c.z);
      float p3 = v.w * (a.w * c.w);
      wt  += p0 + p1 + p2 + p3;
      vsq += p0 * p0 + p1 * p1 + p2 * p2 + p3 * p3;
    }
    if (valid) wts[e] = wt;
    if (valid && lvl && (uint32_t)(e - L1N) < (uint32_t)KEEP2) v2acc += vsq;
  }

  // ---- phase D2: MLP hidden layer, bf16x3 MFMA GEMM (h = Z_sel@W1 + b1) ----
  // acc += Ah*Bh + Al*Bh + Ah*Bl (same order as R5-R7). Bh cached in regs
  // (32 VGPR); Bl streamed from W1loT via ds_read_b128.
  {
    const int lane = tid & 63;
    const int wave = tid >> 6;
    const int col  = lane & 15;   // A-row / D-col / B-col within 16-tile
    const int kg   = lane >> 4;   // k-group: this lane's 8 contiguous k

    bf16x8 Bh[2][4];
#pragma unroll
    for (int ks = 0; ks < 2; ++ks)
#pragma unroll
      for (int c = 0; c < 4; ++c) {
        const float* wp = &W1[(ks * 32 + kg * 8) * 64 + c * 16 + col];
#pragma unroll
        for (int j = 0; j < 8; ++j)
          Bh[ks][c][j] = (short)bf_rne(wp[j * 64]);
      }
    float bv0 = b1[col], bv1 = b1[16 + col], bv2 = b1[32 + col], bv3 = b1[48 + col];

    for (int t = wave; t < NT; t += 4) {
      const int er = 16 * t + col;
      const uint32_t dsc = (uint32_t)descs16[er];
      const int oI = (int)(dsc & 31) * ROWP;
      const int oJ = (int)((dsc >> 5) & 31) * ROWP;
      const int oL = (int)((dsc >> 10) & 31) * ROWP;

      f32x4 acc[4];
      acc[0] = (f32x4){bv0, bv0, bv0, bv0};
      acc[1] = (f32x4){bv1, bv1, bv1, bv1};
      acc[2] = (f32x4){bv2, bv2, bv2, bv2};
      acc[3] = (f32x4){bv3, bv3, bv3, bv3};

#pragma unroll
      for (int ks = 0; ks < 2; ++ks) {
        const int kc = ks * 32 + kg * 8;
        float4 a0 = *(const float4*)&Z0s[oJ + kc];
        float4 c0 = *(const float4*)&Z0s[oL + kc];
        float4 z0 = *(const float4*)&Z0s[oI + kc];
        float4 a1 = *(const float4*)&Z0s[oJ + kc + 4];
        float4 c1 = *(const float4*)&Z0s[oL + kc + 4];
        float4 z1 = *(const float4*)&Z0s[oI + kc + 4];
        float z[8];
        z[0] = z0.x * (a0.x * c0.x);  z[1] = z0.y * (a0.y * c0.y);
        z[2] = z0.z * (a0.z * c0.z);  z[3] = z0.w * (a0.w * c0.w);
        z[4] = z1.x * (a1.x * c1.x);  z[5] = z1.y * (a1.y * c1.y);
        z[6] = z1.z * (a1.z * c1.z);  z[7] = z1.w * (a1.w * c1.w);

        ABfrag Ah, Al;
#pragma unroll
        for (int p = 0; p < 4; ++p) {
          uint32_t uz0 = __float_as_uint(z[2 * p]);
          uint32_t uz1 = __float_as_uint(z[2 * p + 1]);
          Ah.u[p] = __builtin_amdgcn_perm(uz1, uz0, 0x07060302u);
          float hf0 = __uint_as_float(uz0 & 0xffff0000u);
          float hf1 = __uint_as_float(uz1 & 0xffff0000u);
          uint32_t d0 = __float_as_uint(z[2 * p]     - hf0);
          uint32_t d1 = __float_as_uint(z[2 * p + 1] - hf1);
          d0 = d0 + 0x7fffu + ((d0 >> 16) & 1u);   // rne to bf16 (in hi word)
          d1 = d1 + 0x7fffu + ((d1 >> 16) & 1u);
          Al.u[p] = __builtin_amdgcn_perm(d1, d0, 0x07060302u);
        }
#pragma unroll
        for (int c = 0; c < 4; ++c)
          acc[c] = __builtin_amdgcn_mfma_f32_16x16x32_bf16(Ah.v, Bh[ks][c], acc[c], 0, 0, 0);
#pragma unroll
        for (int c = 0; c < 4; ++c)
          acc[c] = __builtin_amdgcn_mfma_f32_16x16x32_bf16(Al.v, Bh[ks][c], acc[c], 0, 0, 0);
#pragma unroll
        for (int c = 0; c < 4; ++c) {
          bf16x8 Blf = *(const bf16x8*)&W1loT[(c * 16 + col) * WLOS + ks * 32 + kg * 8];
          acc[c] = __builtin_amdgcn_mfma_f32_16x16x32_bf16(Ah.v, Blf, acc[c], 0, 0, 0);
        }
      }

      // second layer: t2 = relu(h) @ W2, reduced across the 16 cols
      float p0 = 0.f, p1 = 0.f, p2 = 0.f, p3 = 0.f;
#pragma unroll
      for (int c = 0; c < 4; ++c) {
        float w2v = W2s[c * 16 + col];
        p0 = fmaf(fmaxf(acc[c][0], 0.f), w2v, p0);
        p1 = fmaf(fmaxf(acc[c][1], 0.f), w2v, p1);
        p2 = fmaf(fmaxf(acc[c][2], 0.f), w2v, p2);
        p3 = fmaf(fmaxf(acc[c][3], 0.f), w2v, p3);
      }
#pragma unroll
      for (int m = 1; m < 16; m <<= 1) {
        p0 += __shfl_xor(p0, m, 16);
        p1 += __shfl_xor(p1, m, 16);
        p2 += __shfl_xor(p2, m, 16);
        p3 += __shfl_xor(p3, m, 16);
      }
      const int rb = 16 * t + kg * 4;   // D rows this lane-group owns
      if      (col == 0) t2s[rb + 0] = p0;
      else if (col == 1) t2s[rb + 1] = p1;
      else if (col == 2) t2s[rb + 2] = p2;
      else if (col == 3) t2s[rb + 3] = p3;
    }
  }
  __syncthreads();

  // ---- phase D3: eps (threefry), sigmoid (fast f32 + guarded f64), gate ----
  uint32_t fkA0, fkA1, fkB0, fkB1;   // fold_in(key(42), 0) and (.,1)
  tf2x32(0u, 42u, 0u, 0u, fkA0, fkA1);
  tf2x32(0u, 42u, 0u, 1u, fkB0, fkB1);
  const float b2v = b2[0];

  float yacc = 0.f;
  for (int e0 = 0; e0 < 768; e0 += 256) {
    const int e = e0 + tid;
    const bool valid = (e < NE);
    uint32_t dsc = valid ? (uint32_t)descs16[e] : 0x4210u;
    const int lvl = (dsc >> 15) & 1;

    float t2 = (valid ? t2s[e] : 0.f) + b2v;

    uint32_t Lsz  = lvl ? (uint32_t)L2N : (uint32_t)L1N;
    uint32_t lidx = lvl ? (uint32_t)(e - L1N) : (uint32_t)e;
    uint32_t kk0  = lvl ? fkB0 : fkA0;
    uint32_t kk1  = lvl ? fkB1 : fkA1;
    uint32_t gi   = (uint32_t)b * Lsz + lidx;
    uint32_t o0, o1, bits;
#if THREEFRY_PARTITIONABLE
    tf2x32(kk0, kk1, 0u, gi, o0, o1);
    bits = o0 ^ o1;
#else
    {
      uint32_t half = Lsz * (NB / 2);
      if (gi < half) { tf2x32(kk0, kk1, gi, gi + half, o0, o1); bits = o0; }
      else           { tf2x32(kk0, kk1, gi - half, gi, o0, o1); bits = o1; }
    }
#endif
    float eps = __uint_as_float((bits >> 9) | 0x3f800000u) - 1.0f;

    // fast f32 sigmoid; exact f64 only in the ambiguity window. Decisions
    // identical to the pure-f64 path: |pf - pro_f64| < ~3e-6 << 1e-4.
    // (validated: absmax 0.0 in R8 and R9)
    float pf = 1.0f / (1.0f + __expf(-t2));
    bool gate;
    if (fabsf(pf - eps) > 1e-4f) {
      gate = (pf >= eps);
    } else {
      double ex = exp(-(double)t2);
      float pro = (float)(1.0 / (1.0 + ex));
      gate = (pro >= eps);
    }
    if (valid && gate) yacc += wts[e];
  }

  // ---- phase E: wave-shuffle reduction, one barrier ----
  {
#pragma unroll
    for (int m = 32; m > 0; m >>= 1) {
      yacc  += __shfl_down(yacc, m, 64);
      v2acc += __shfl_down(v2acc, m, 64);
    }
    if ((tid & 63) == 0) {
      red8[tid >> 6]       = yacc;
      red8[4 + (tid >> 6)] = v2acc;
    }
    __syncthreads();
    if (tid == 0) {
      out[b] = w0[0] + wsum_s + ((red8[0] + red8[1]) + (red8[2] + red8[3]));
      reg_partial[b] = w2sum_s + ((red8[4] + red8[5]) + (red8[6] + red8[7]));
    }
  }
}

__global__ __launch_bounds__(256) void sfis_reduce(
    const float* __restrict__ reg_partial, float* __restrict__ out) {
  __shared__ float red[256];
  int tid = threadIdx.x;
  float s = 0.f;
  for (int i = tid; i < NB; i += 256) s += reg_partial[i];
  red[tid] = s;
  __syncthreads();
  for (int st = 128; st > 0; st >>= 1) {
    if (tid < st) red[tid] += red[tid + st];
    __syncthreads();
  }
  if (tid == 0) out[NB] = 1.0e-4f * red[0];  // BETA
}

extern "C" void kernel_launch(void* const* d_in, const int* in_sizes, int n_in,
                              void* d_out, int out_size, void* d_ws, size_t ws_size,
                              hipStream_t stream) {
  (void)in_sizes; (void)n_in; (void)out_size; (void)ws_size;
  const int*   x       = (const int*)  d_in[0];
  const float* M       = (const float*)d_in[1];
  const float* w0      = (const float*)d_in[2];
  const float* w_table = (const float*)d_in[3];
  const float* V_table = (const float*)d_in[4];
  const float* Z_table = (const float*)d_in[5];
  const float* W1      = (const float*)d_in[6];
  const float* b1      = (const float*)d_in[7];
  const float* W2      = (const float*)d_in[8];
  const float* b2      = (const float*)d_in[9];
  float* out  = (float*)d_out;
  float* regp = (float*)d_ws;   // 2048 partials

  hipLaunchKernelGGL(sfis_main, dim3(NB), dim3(256), 0, stream,
                     x, M, w0, w_table, V_table, Z_table, W1, b1, W2, b2,
                     out, regp);
  hipLaunchKernelGGL(sfis_reduce, dim3(1), dim3(256), 0, stream, regp, out);
}

// Round 11
// 80.901 us; speedup vs baseline: 1.9148x; 1.0830x over previous
//
#include <hip/hip_runtime.h>
#include <stdint.h>
#include <math.h>

// SFIS: F=16, D=64, N=100000, B=2048, ORDER=3, BETA=1e-4, H=64
#define NB    2048
#define NE    680     // 120 pairs + 560 triples
#define L1N   120
#define L2N   560
#define KEEP2 455     // triples with A<=12 feed the regularizer
#define ROWP  68      // padded LDS row stride (floats) for V0s/Z0s
#define NT    43      // 16-row MFMA tiles covering 688 >= 680 rows
#define NSL   688     // NT*16
#define WLOS  72      // W1loT LDS row stride in ushorts (pad: bank-balanced b128)

#define THREEFRY_PARTITIONABLE 1

typedef __attribute__((ext_vector_type(8))) short bf16x8;
typedef __attribute__((ext_vector_type(4))) float f32x4;
typedef __attribute__((ext_vector_type(4))) uint32_t u32x4;

union ABfrag { bf16x8 v; uint32_t u[4]; };

__device__ __forceinline__ uint32_t rotl32(uint32_t v, uint32_t d) {
  return (v << d) | (v >> (32u - d));
}

// f32 -> bf16 bits, round-nearest-even (finite inputs only)
__device__ __forceinline__ uint32_t bf_rne(float f) {
  uint32_t u = __float_as_uint(f);
  return (u + 0x7fffu + ((u >> 16) & 1u)) >> 16;
}

// JAX threefry2x32 (jax/_src/prng.py), 20 rounds.
__device__ __forceinline__ void tf2x32(uint32_t k0, uint32_t k1,
                                       uint32_t c0, uint32_t c1,
                                       uint32_t &o0, uint32_t &o1) {
  uint32_t ks2 = k0 ^ k1 ^ 0x1BD11BDAu;
  uint32_t x0 = c0 + k0;
  uint32_t x1 = c1 + k1;
#define TF_R(r) { x0 += x1; x1 = rotl32(x1, r); x1 ^= x0; }
  TF_R(13) TF_R(15) TF_R(26) TF_R(6)
  x0 += k1;  x1 += ks2 + 1u;
  TF_R(17) TF_R(29) TF_R(16) TF_R(24)
  x0 += ks2; x1 += k0 + 2u;
  TF_R(13) TF_R(15) TF_R(26) TF_R(6)
  x0 += k0;  x1 += k1 + 3u;
  TF_R(17) TF_R(29) TF_R(16) TF_R(24)
  x0 += k1;  x1 += ks2 + 4u;
  TF_R(13) TF_R(15) TF_R(26) TF_R(6)
  x0 += ks2; x1 += k0 + 5u;
#undef TF_R
  o0 = x0; o1 = x1;
}

// One-shot per-launch precompute of block-invariant data (descs + W1 splits
// in fragment layout [n][k]). Grid = 17 blocks: 0..15 split W1, 16 builds descs.
__global__ __launch_bounds__(256) void sfis_setup(
    const float* __restrict__ W1,
    unsigned short* __restrict__ ws_descs,   // [688]
    unsigned short* __restrict__ ws_w1hi,    // [64][64], n-major
    unsigned short* __restrict__ ws_w1lo) {  // [64][64], n-major
  const int bid = blockIdx.x, tid = threadIdx.x;
  if (bid == 16) {
    for (int e = tid; e < NSL; e += 256) {
      int fi, fj, fl, lvl;
      if (e < L1N) {                      // pair: V0f[a+1] * V0f[k]
        int a = 0;
        while ((a + 1) * (a + 2) / 2 <= e) ++a;
        int k = e - a * (a + 1) / 2;
        fi = a + 1; fj = k; fl = 16; lvl = 0;   // fl=16 -> ones row
      } else if (e < NE) {                // triple: V0f[A+2] * (V0f[a1+1]*V0f[k1])
        int e2 = e - L1N;
        int A = 0;
        while ((A + 1) * (A + 2) * (A + 3) / 6 <= e2) ++A;
        int k = e2 - A * (A + 1) * (A + 2) / 6;
        int a1 = 0;
        while ((a1 + 1) * (a1 + 2) / 2 <= k) ++a1;
        int k1 = k - a1 * (a1 + 1) / 2;
        fi = A + 2; fj = a1 + 1; fl = k1; lvl = 1;
      } else {                            // dummy rows 680..687 -> ones product
        fi = 16; fj = 16; fl = 16; lvl = 0;
      }
      ws_descs[e] = (unsigned short)((uint32_t)fi | ((uint32_t)fj << 5) |
                                     ((uint32_t)fl << 10) | ((uint32_t)lvl << 15));
    }
  } else {
    int i = bid * 256 + tid;            // i = k*64 + n over W1[64][64]
    int k = i >> 6, n = i & 63;
    float w = W1[i];
    uint32_t hb = bf_rne(w);
    float hf = __uint_as_float(hb << 16);
    uint32_t lb = bf_rne(w - hf);
    ws_w1hi[n * 64 + k] = (unsigned short)hb;
    ws_w1lo[n * 64 + k] = (unsigned short)lb;
  }
}

// R7 champion shape: 256 threads, ~25.5 KB LDS (6 blocks/CU), Bh in regs,
// Bl streamed from LDS. VGPR ~80. Do NOT grow LDS or merge phases (R6/R8/R9).
__global__ __launch_bounds__(256, 8) void sfis_main(
    const int*   __restrict__ x,
    const float* __restrict__ M,
    const float* __restrict__ w0,
    const float* __restrict__ w_table,
    const float* __restrict__ V_table,
    const float* __restrict__ Z_table,
    const float* __restrict__ b1,
    const float* __restrict__ W2,
    const float* __restrict__ b2,
    const unsigned short* __restrict__ ws_descs,
    const unsigned short* __restrict__ ws_w1hi,
    const unsigned short* __restrict__ ws_w1lo,
    float* __restrict__ out,
    float* __restrict__ reg_partial) {
  __shared__ __align__(16) float V0s[17 * ROWP];  // row 16 = ones
  __shared__ __align__(16) float Z0s[17 * ROWP];
  __shared__ __align__(16) unsigned short W1loT[64 * WLOS];
  __shared__ __align__(4) unsigned short descs16[NSL];
  __shared__ float wts[NSL];
  __shared__ float t2s[NSL];
  __shared__ float W2s[64];
  __shared__ int xs[16];
  __shared__ float red8[8];
  __shared__ float wsum_s, w2sum_s;

  const int b   = blockIdx.x;
  const int tid = threadIdx.x;

  // ---- phase A: indices, ones rows, copy precomputed descs + W1lo table ----
  if (tid < 16) xs[tid] = x[b * 16 + tid];
  if (tid < 64) {
    W2s[tid] = W2[tid];
    V0s[16 * ROWP + tid] = 1.f;
    Z0s[16 * ROWP + tid] = 1.f;
  }
  for (int i = tid; i < NSL / 2; i += 256)    // 344 dwords
    ((uint32_t*)descs16)[i] = ((const uint32_t*)ws_descs)[i];
  for (int i = tid; i < 512; i += 256) {      // 64 rows x 8 chunks of 16B
    int n = i >> 3, ch = i & 7;
    *(u32x4*)((char*)W1loT + n * (WLOS * 2) + ch * 16) =
        *(const u32x4*)((const char*)ws_w1lo + n * 128 + ch * 16);
  }
  __syncthreads();

  // ---- phase C: V0f = M @ V, Z0f = M @ Z (from global; rows are L1-hot) ----
  if (tid == 0) {
    float s = 0.f, s2 = 0.f;
    for (int f = 0; f < 16; ++f) {
      float wv = w_table[xs[f]];
      s += wv; s2 += wv * wv;
    }
    wsum_s = s; w2sum_s = s2;
  }
  for (int idx = tid; idx < 1024; idx += 256) {
    int f = idx >> 6, d = idx & 63;
    float av = 0.f, az = 0.f;
    for (int g = 0; g < 16; ++g) {
      float m = M[f * 16 + g];          // wave-uniform -> s_load
      long off = (long)xs[g] * 64 + d;  // coalesced over d
      av = fmaf(m, V_table[off], av);
      az = fmaf(m, Z_table[off], az);
    }
    V0s[f * ROWP + d] = av;
    Z0s[f * ROWP + d] = az;
  }
  __syncthreads();

  // ---- phase D1: Wt / vsq on VALU; Wt -> LDS ----
  float v2acc = 0.f;
  for (int e0 = 0; e0 < 768; e0 += 256) {
    const int e = e0 + tid;
    const bool valid = (e < NE);
    uint32_t dsc = valid ? (uint32_t)descs16[e] : 0x4210u;
    const int oI = (int)(dsc & 31) * ROWP;
    const int oJ = (int)((dsc >> 5) & 31) * ROWP;
    const int oL = (int)((dsc >> 10) & 31) * ROWP;
    const int lvl = (dsc >> 15) & 1;

    float wt = 0.f, vsq = 0.f;
    for (int dq = 0; dq < 16; ++dq) {
      float4 a = *(const float4*)&V0s[oJ + (dq << 2)];
      float4 c = *(const float4*)&V0s[oL + (dq << 2)];
      float4 v = *(const float4*)&V0s[oI + (dq << 2)];
      float p0 = v.x * (a.x * c.x);
      float p1 = v.y * (a.y * c.y);
      float p2 = v.z * (a.z * c.z);
      float p3 = v.w * (a.w * c.w);
      wt  += p0 + p1 + p2 + p3;
      vsq += p0 * p0 + p1 * p1 + p2 * p2 + p3 * p3;
    }
    if (valid) wts[e] = wt;
    if (valid && lvl && (uint32_t)(e - L1N) < (uint32_t)KEEP2) v2acc += vsq;
  }

  // ---- phase D2: MLP hidden layer, bf16x3 MFMA GEMM (h = Z_sel@W1 + b1) ----
  // acc += Ah*Bh + Al*Bh + Ah*Bl. Ah = trunc(z), Al = trunc(z - Ah) [residual
  // capture 2^-16|z| -- gate-flip expectation ~3e-3 over 1.4M gates].
  // Bh loaded as prebuilt fragments (16B loads); Bl streamed from W1loT LDS.
  {
    const int lane = tid & 63;
    const int wave = tid >> 6;
    const int col  = lane & 15;   // A-row / D-col / B-col within 16-tile
    const int kg   = lane >> 4;   // k-group: this lane's 8 contiguous k

    bf16x8 Bh[2][4];
#pragma unroll
    for (int ks = 0; ks < 2; ++ks)
#pragma unroll
      for (int c = 0; c < 4; ++c)
        Bh[ks][c] = *(const bf16x8*)&ws_w1hi[(c * 16 + col) * 64 + ks * 32 + kg * 8];
    float bv0 = b1[col], bv1 = b1[16 + col], bv2 = b1[32 + col], bv3 = b1[48 + col];

    for (int t = wave; t < NT; t += 4) {
      const int er = 16 * t + col;
      const uint32_t dsc = (uint32_t)descs16[er];
      const int oI = (int)(dsc & 31) * ROWP;
      const int oJ = (int)((dsc >> 5) & 31) * ROWP;
      const int oL = (int)((dsc >> 10) & 31) * ROWP;

      f32x4 acc[4];
      acc[0] = (f32x4){bv0, bv0, bv0, bv0};
      acc[1] = (f32x4){bv1, bv1, bv1, bv1};
      acc[2] = (f32x4){bv2, bv2, bv2, bv2};
      acc[3] = (f32x4){bv3, bv3, bv3, bv3};

#pragma unroll
      for (int ks = 0; ks < 2; ++ks) {
        const int kc = ks * 32 + kg * 8;
        float4 a0 = *(const float4*)&Z0s[oJ + kc];
        float4 c0 = *(const float4*)&Z0s[oL + kc];
        float4 z0 = *(const float4*)&Z0s[oI + kc];
        float4 a1 = *(const float4*)&Z0s[oJ + kc + 4];
        float4 c1 = *(const float4*)&Z0s[oL + kc + 4];
        float4 z1 = *(const float4*)&Z0s[oI + kc + 4];
        float z[8];
        z[0] = z0.x * (a0.x * c0.x);  z[1] = z0.y * (a0.y * c0.y);
        z[2] = z0.z * (a0.z * c0.z);  z[3] = z0.w * (a0.w * c0.w);
        z[4] = z1.x * (a1.x * c1.x);  z[5] = z1.y * (a1.y * c1.y);
        z[6] = z1.z * (a1.z * c1.z);  z[7] = z1.w * (a1.w * c1.w);

        ABfrag Ah, Al;
#pragma unroll
        for (int p = 0; p < 4; ++p) {
          uint32_t uz0 = __float_as_uint(z[2 * p]);
          uint32_t uz1 = __float_as_uint(z[2 * p + 1]);
          Ah.u[p] = __builtin_amdgcn_perm(uz1, uz0, 0x07060302u);
          float hf0 = __uint_as_float(uz0 & 0xffff0000u);
          float hf1 = __uint_as_float(uz1 & 0xffff0000u);
          uint32_t d0 = __float_as_uint(z[2 * p]     - hf0);
          uint32_t d1 = __float_as_uint(z[2 * p + 1] - hf1);
          Al.u[p] = __builtin_amdgcn_perm(d1, d0, 0x07060302u);  // truncation
        }
#pragma unroll
        for (int c = 0; c < 4; ++c)
          acc[c] = __builtin_amdgcn_mfma_f32_16x16x32_bf16(Ah.v, Bh[ks][c], acc[c], 0, 0, 0);
#pragma unroll
        for (int c = 0; c < 4; ++c)
          acc[c] = __builtin_amdgcn_mfma_f32_16x16x32_bf16(Al.v, Bh[ks][c], acc[c], 0, 0, 0);
#pragma unroll
        for (int c = 0; c < 4; ++c) {
          bf16x8 Blf = *(const bf16x8*)&W1loT[(c * 16 + col) * WLOS + ks * 32 + kg * 8];
          acc[c] = __builtin_amdgcn_mfma_f32_16x16x32_bf16(Ah.v, Blf, acc[c], 0, 0, 0);
        }
      }

      // second layer: t2 = relu(h) @ W2, reduced across the 16 cols
      float p0 = 0.f, p1 = 0.f, p2 = 0.f, p3 = 0.f;
#pragma unroll
      for (int c = 0; c < 4; ++c) {
        float w2v = W2s[c * 16 + col];
        p0 = fmaf(fmaxf(acc[c][0], 0.f), w2v, p0);
        p1 = fmaf(fmaxf(acc[c][1], 0.f), w2v, p1);
        p2 = fmaf(fmaxf(acc[c][2], 0.f), w2v, p2);
        p3 = fmaf(fmaxf(acc[c][3], 0.f), w2v, p3);
      }
#pragma unroll
      for (int m = 1; m < 16; m <<= 1) {
        p0 += __shfl_xor(p0, m, 16);
        p1 += __shfl_xor(p1, m, 16);
        p2 += __shfl_xor(p2, m, 16);
        p3 += __shfl_xor(p3, m, 16);
      }
      const int rb = 16 * t + kg * 4;   // D rows this lane-group owns
      if      (col == 0) t2s[rb + 0] = p0;
      else if (col == 1) t2s[rb + 1] = p1;
      else if (col == 2) t2s[rb + 2] = p2;
      else if (col == 3) t2s[rb + 3] = p3;
    }
  }
  __syncthreads();

  // ---- phase D3: eps (threefry), sigmoid (fast f32 + guarded f64), gate ----
  uint32_t fkA0, fkA1, fkB0, fkB1;   // fold_in(key(42), 0) and (.,1)
  tf2x32(0u, 42u, 0u, 0u, fkA0, fkA1);
  tf2x32(0u, 42u, 0u, 1u, fkB0, fkB1);
  const float b2v = b2[0];

  float yacc = 0.f;
  for (int e0 = 0; e0 < 768; e0 += 256) {
    const int e = e0 + tid;
    const bool valid = (e < NE);
    uint32_t dsc = valid ? (uint32_t)descs16[e] : 0x4210u;
    const int lvl = (dsc >> 15) & 1;

    float t2 = (valid ? t2s[e] : 0.f) + b2v;

    uint32_t Lsz  = lvl ? (uint32_t)L2N : (uint32_t)L1N;
    uint32_t lidx = lvl ? (uint32_t)(e - L1N) : (uint32_t)e;
    uint32_t kk0  = lvl ? fkB0 : fkA0;
    uint32_t kk1  = lvl ? fkB1 : fkA1;
    uint32_t gi   = (uint32_t)b * Lsz + lidx;
    uint32_t o0, o1, bits;
#if THREEFRY_PARTITIONABLE
    tf2x32(kk0, kk1, 0u, gi, o0, o1);
    bits = o0 ^ o1;
#else
    {
      uint32_t half = Lsz * (NB / 2);
      if (gi < half) { tf2x32(kk0, kk1, gi, gi + half, o0, o1); bits = o0; }
      else           { tf2x32(kk0, kk1, gi - half, gi, o0, o1); bits = o1; }
    }
#endif
    float eps = __uint_as_float((bits >> 9) | 0x3f800000u) - 1.0f;

    // fast f32 sigmoid; exact f64 only in the ambiguity window. Decisions
    // identical to the pure-f64 path (validated R8-R10, absmax 0.0).
    float pf = 1.0f / (1.0f + __expf(-t2));
    bool gate;
    if (fabsf(pf - eps) > 1e-4f) {
      gate = (pf >= eps);
    } else {
      double ex = exp(-(double)t2);
      float pro = (float)(1.0 / (1.0 + ex));
      gate = (pro >= eps);
    }
    if (valid && gate) yacc += wts[e];
  }

  // ---- phase E: wave-shuffle reduction, one barrier ----
  {
#pragma unroll
    for (int m = 32; m > 0; m >>= 1) {
      yacc  += __shfl_down(yacc, m, 64);
      v2acc += __shfl_down(v2acc, m, 64);
    }
    if ((tid & 63) == 0) {
      red8[tid >> 6]       = yacc;
      red8[4 + (tid >> 6)] = v2acc;
    }
    __syncthreads();
    if (tid == 0) {
      out[b] = w0[0] + wsum_s + ((red8[0] + red8[1]) + (red8[2] + red8[3]));
      reg_partial[b] = w2sum_s + ((red8[4] + red8[5]) + (red8[6] + red8[7]));
    }
  }
}

__global__ __launch_bounds__(256) void sfis_reduce(
    const float* __restrict__ reg_partial, float* __restrict__ out) {
  __shared__ float red[256];
  int tid = threadIdx.x;
  float s = 0.f;
  for (int i = tid; i < NB; i += 256) s += reg_partial[i];
  red[tid] = s;
  __syncthreads();
  for (int st = 128; st > 0; st >>= 1) {
    if (tid < st) red[tid] += red[tid + st];
    __syncthreads();
  }
  if (tid == 0) out[NB] = 1.0e-4f * red[0];  // BETA
}

extern "C" void kernel_launch(void* const* d_in, const int* in_sizes, int n_in,
                              void* d_out, int out_size, void* d_ws, size_t ws_size,
                              hipStream_t stream) {
  (void)in_sizes; (void)n_in; (void)out_size; (void)ws_size;
  const int*   x       = (const int*)  d_in[0];
  const float* M       = (const float*)d_in[1];
  const float* w0      = (const float*)d_in[2];
  const float* w_table = (const float*)d_in[3];
  const float* V_table = (const float*)d_in[4];
  const float* Z_table = (const float*)d_in[5];
  const float* W1      = (const float*)d_in[6];
  const float* b1      = (const float*)d_in[7];
  const float* W2      = (const float*)d_in[8];
  const float* b2      = (const float*)d_in[9];
  float* out  = (float*)d_out;

  // d_ws layout: [0,1376) descs | [2048,10240) W1hi | [10240,18432) W1lo |
  //              [20480, +8KB) reg partials
  unsigned short* ws_descs = (unsigned short*)d_ws;
  unsigned short* ws_w1hi  = (unsigned short*)((char*)d_ws + 2048);
  unsigned short* ws_w1lo  = (unsigned short*)((char*)d_ws + 10240);
  float*          regp     = (float*)((char*)d_ws + 20480);

  hipLaunchKernelGGL(sfis_setup, dim3(17), dim3(256), 0, stream,
                     W1, ws_descs, ws_w1hi, ws_w1lo);
  hipLaunchKernelGGL(sfis_main, dim3(NB), dim3(256), 0, stream,
                     x, M, w0, w_table, V_table, Z_table, b1, W2, b2,
                     ws_descs, ws_w1hi, ws_w1lo, out, regp);
  hipLaunchKernelGGL(sfis_reduce, dim3(1), dim3(256), 0, stream, regp, out);
}